// Round 16
// baseline (1443.823 us; speedup 1.0000x reference)
//
#include <hip/hip_runtime.h>
#include <cmath>

#define TT 1024
#define BB 256
#define GG 16            // batch elements per block (MFMA N)
#define NBLK (BB / GG)   // 16 producer blocks + 16 consumer blocks

#define LOG2E  1.4426950408889634f
#define LOG2E2 2.8853900817779268f   // 2*log2(e)

typedef _Float16 f16x8 __attribute__((ext_vector_type(8)));
typedef float    f32x4 __attribute__((ext_vector_type(4)));
typedef _Float16 half2v __attribute__((ext_vector_type(2)));

__device__ __forceinline__ float fast_rcp(float x) { return __builtin_amdgcn_rcpf(x); }
__device__ __forceinline__ unsigned pack_f16(float a, float b) {
    half2v h; h.x = (_Float16)a; h.y = (_Float16)b;
    return __builtin_bit_cast(unsigned, h);
}
__device__ __forceinline__ void pin4(uint4& u) {
    asm volatile("" : "+v"(u.x), "+v"(u.y), "+v"(u.z), "+v"(u.w));
}
__device__ __forceinline__ f16x8 h8(uint4 u) { return __builtin_bit_cast(f16x8, u); }
// LDS-ordered barrier that does NOT drain vmcnt (global stores stay in flight).
__device__ __forceinline__ void step_barrier() {
    asm volatile("s_waitcnt lgkmcnt(0)" ::: "memory");
    __builtin_amdgcn_s_barrier();
}

// Fused LSTM cell update with shared reciprocals: 7 transcendentals/cell
// (4+1 exp2, 2 rcp) instead of 10. Inputs pre-scaled: gi,gf,go by log2e,
// gg by 2*log2e. Upper clamps keep products < f32 max; exp2 underflow -> 0
// yields exact saturation limits. D,V >= 1 so rcp is safe.
__device__ __forceinline__ float lstm_cell(float gi, float gf, float gg,
                                           float go, float& c) {
    float Ei = __builtin_exp2f(fminf(gi, 17.f));
    float Ef = __builtin_exp2f(fminf(gf, 17.f));
    float Eg = __builtin_exp2f(fminf(gg, 30.f));
    float Eo = __builtin_exp2f(fminf(go, 17.f));
    float t1 = 1.f + Ei, t2 = Eg + 1.f, t3 = Eg - 1.f, t4 = 1.f + Ef;
    float d  = t1 * t2;
    float num = fmaf(Ef * c, d, (Ei * t3) * t4);
    c = num * fast_rcp(d * t4);
    float Ec = __builtin_exp2f(fminf(c * LOG2E2, 30.f));
    float V  = (Ec + 1.f) * (1.f + Eo);
    return (Eo * (Ec - 1.f)) * fast_rcp(V);
}

#define MFMA16(a, b, c) __builtin_amdgcn_mfma_f32_16x16x32_f16((a), (b), (c), 0, 0, 0)
#define ZERO4 ((f32x4){0.f, 0.f, 0.f, 0.f})

// Fragment addressing: element (k, col) of a B-frag tile set lives at
// buf[k>>5][((k&31)>>3)*16 + col] byte (k&7)*2.
#define FRAG_PTR(buf, k, col) ((char*)&(buf)[(k) >> 5][(((k) & 31) >> 3) * 16 + (col)] + ((k) & 7) * 2)

// ============================================================================
// prep = weight reorder (fp16 A-frags, pre-scaled) + x pre-pack + prog zero,
// fused into one launch. Blocks [0,561) = reorder+flags; [561, 561+13312) = x.
// ============================================================================
__global__ __launch_bounds__(256) void prep(
    const float* __restrict__ Wih0, const float* __restrict__ Whh0,
    const float* __restrict__ Wih1, const float* __restrict__ Whh1,
    const float* __restrict__ Wih2, const float* __restrict__ Whh2,
    const float* __restrict__ x,
    _Float16* __restrict__ wfA0, _Float16* __restrict__ wfA1,
    _Float16* __restrict__ wfC, int* __restrict__ prog,
    uint4* __restrict__ xf123, uint2* __restrict__ xf4c)
{
    if (blockIdx.x < 561) {
        int idx = blockIdx.x * 256 + threadIdx.x;
        if (idx < 98304) {                       // C section
            int j = idx & 7, l = (idx >> 3) & 63, t = idx >> 9;
            int kt = t % 6, g = (t / 6) & 3, w = t / 24;
            int row = g * 128 + 16 * w + (l & 15);
            int k = kt * 32 + ((l >> 4) << 3) + j;
            float sc = (g == 2) ? LOG2E2 : LOG2E;
            float v = (k < 64) ? Wih2[row * 64 + k] : Whh2[row * 128 + (k - 64)];
            wfC[idx] = (_Float16)(v * sc);
        } else if (idx < 118784) {               // A0 section: K-order [h0|x|pad]
            int f = idx - 98304;
            int j = f & 7, l = (f >> 3) & 63, t = f >> 9;
            int kt = t % 5, g = (t / 5) & 3, w = t / 20;
            int row = g * 32 + 16 * w + (l & 15);
            int k = kt * 32 + ((l >> 4) << 3) + j;
            float sc = (g == 2) ? LOG2E2 : LOG2E;
            float v = (k < 32)  ? Whh0[row * 32 + k]
                    : (k < 132) ? Wih0[row * 100 + (k - 32)] : 0.0f;
            wfA0[f] = (_Float16)(v * sc);
        } else if (idx < 143360) {               // A1 section
            int f = idx - 118784;
            int j = f & 7, l = (f >> 3) & 63, t = f >> 9;
            int kt = t % 3, g = (t / 3) & 3, w = t / 12;
            int row = g * 64 + 16 * w + (l & 15);
            int k = kt * 32 + ((l >> 4) << 3) + j;
            float sc = (g == 2) ? LOG2E2 : LOG2E;
            float v = (k < 32) ? Wih1[row * 32 + k] : Whh1[row * 64 + (k - 32)];
            wfA1[f] = (_Float16)(v * sc);
        } else if (idx < 143376) {               // progress flags
            prog[idx - 143360] = 0;
        }
    } else {
        int idx = (blockIdx.x - 561) * 256 + threadIdx.x;
        if (idx < 16 * 1024 * 3 * 64) {
            int l   = idx & 63;
            int kt  = (idx >> 6) % 3;
            int t   = ((idx >> 6) / 3) & 1023;
            int blk = (idx >> 6) / 3 / 1024;
            int col = l & 15, lq = l >> 4;
            int xidx = kt * 32 + lq * 8;
            const float* xr = x + ((size_t)(blk * GG + col) * TT + t) * 100 + xidx;
            float4 a = *reinterpret_cast<const float4*>(xr);
            float4 b = *reinterpret_cast<const float4*>(xr + 4);
            uint4 u;
            u.x = pack_f16(a.x, a.y); u.y = pack_f16(a.z, a.w);
            u.z = pack_f16(b.x, b.y); u.w = pack_f16(b.z, b.w);
            xf123[idx] = u;
        } else {
            int f = idx - 16 * 1024 * 3 * 64;     // exactly 16*1024*16 threads
            int col = f & 15;
            int t   = (f >> 4) & 1023;
            int blk = f >> 14;
            const float* xr = x + ((size_t)(blk * GG + col) * TT + t) * 100 + 96;
            float4 a = *reinterpret_cast<const float4*>(xr);
            uint2 u; u.x = pack_f16(a.x, a.y); u.y = pack_f16(a.z, a.w);
            xf4c[f] = u;
        }
    }
}

// ============================================================================
// Mega kernel: 32 blocks x 512 threads. (Structure identical to R15; only
// the activation is the 7-trans fused form.)
//   blocks 0..15  = A-role: L0 (waves 0-1) + L1 (waves 2-5, lagged 1 step);
//                   wave 6 = store pipeline (r1f stores + drains + publish).
//   blocks 16..31 = C-role: L2, gated every 16 steps, prefetch depth 2,
//                   nontemporal r2 stores.
// ============================================================================
__global__ __attribute__((amdgpu_flat_work_group_size(512, 512),
                          amdgpu_waves_per_eu(1, 2)))
void lstm_mega(const uint4* __restrict__ xf123,
               const uint2* __restrict__ xf4c,
               const _Float16* __restrict__ wfA0,
               const _Float16* __restrict__ wfA1,
               const _Float16* __restrict__ wfC,
               const float* __restrict__ b0_,     // [128]
               const float* __restrict__ b1_,     // [256]
               const float* __restrict__ b2_,     // [512]
               const float* __restrict__ h_0,     // [1, B, 32]
               const float* __restrict__ c_0,     // [1, B, 32]
               uint4* __restrict__ r1f,           // [16][1024][2][64]
               float* __restrict__ r2,            // [B, T, 128]
               int* __restrict__ prog)            // [16]
{
    const int tid = threadIdx.x;
    const int w = tid >> 6, l = tid & 63;
    const int l15 = l & 15, lq = l >> 4;
    const bool isA = (blockIdx.x < NBLK);
    const int blk = isA ? blockIdx.x : blockIdx.x - NBLK;
    const int b0b = blk * GG;

    __shared__ alignas(16) uint4 H0F[2][1][64];   // A: h0 frag
    __shared__ alignas(16) uint4 H1F[2][2][64];   // A: h1 frags
    __shared__ alignas(16) uint4 H2F[2][4][64];   // C: h2 frags

    if (isA) {
        // ==================== A-role: layers 0+1 ====================
        uint4 afu[20];
        f32x4 biasv[4];
        float c[4] = {0.f, 0.f, 0.f, 0.f};
        int jb = 0;
        if (w < 2) {                               // L0
            jb = 16 * w + 4 * lq;
            const uint4* wf4 = reinterpret_cast<const uint4*>(wfA0);
            #pragma unroll
            for (int g = 0; g < 4; ++g)
                #pragma unroll
                for (int kt = 0; kt < 5; ++kt) {
                    afu[g * 5 + kt] = wf4[((w * 4 + g) * 5 + kt) * 64 + l];
                    pin4(afu[g * 5 + kt]);
                }
            #pragma unroll
            for (int g = 0; g < 4; ++g) {
                float sc = (g == 2) ? LOG2E2 : LOG2E;
                #pragma unroll
                for (int r = 0; r < 4; ++r)
                    biasv[g][r] = b0_[g * 32 + jb + r] * sc;
            }
            #pragma unroll
            for (int r = 0; r < 4; ++r) c[r] = c_0[(b0b + l15) * 32 + jb + r];
        } else if (w < 6) {                        // L1
            const int w1 = w - 2;
            jb = 16 * w1 + 4 * lq;
            const uint4* wf4 = reinterpret_cast<const uint4*>(wfA1);
            #pragma unroll
            for (int g = 0; g < 4; ++g)
                #pragma unroll
                for (int kt = 0; kt < 3; ++kt) {
                    afu[g * 3 + kt] = wf4[((w1 * 4 + g) * 3 + kt) * 64 + l];
                    pin4(afu[g * 3 + kt]);
                }
            #pragma unroll
            for (int g = 0; g < 4; ++g) {
                float sc = (g == 2) ? LOG2E2 : LOG2E;
                #pragma unroll
                for (int r = 0; r < 4; ++r)
                    biasv[g][r] = b1_[g * 64 + jb + r] * sc;
            }
        }

        {   // init LDS: H0F[0] = h_0; H1F[1] = 0
            int col = tid >> 5, u = tid & 31;
            *(_Float16*)FRAG_PTR(H0F[0], u, col) =
                (_Float16)h_0[(b0b + col) * 32 + u];
            if (tid < 128) H1F[1][tid >> 6][tid & 63] = (uint4){0, 0, 0, 0};
        }

        // L0 x prefetch (t=0)
        uint4 bx0 = {0,0,0,0}, bx1 = {0,0,0,0}, bx2 = {0,0,0,0};
        uint2 bx4 = {0, 0};
        if (w < 2) {
            size_t o = ((size_t)blk * TT) * 3 * 64 + l;
            bx0 = xf123[o]; bx1 = xf123[o + 64]; bx2 = xf123[o + 128];
            bx4 = xf4c[((size_t)blk * TT) * 16 + l15];
        }
        step_barrier();

        #pragma unroll 2
        for (int m = 0; m <= TT + 1; ++m) {           // 1026 iters (even)
            const int cur = m & 1, nxt = cur ^ 1;

            if (w < 2) {                                  // ---- L0: h0(m) ----
                uint4 cx0 = bx0, cx1 = bx1, cx2 = bx2;
                uint2 cx4 = bx4;
                if (m + 1 < TT) {
                    size_t o = ((size_t)blk * TT + (m + 1)) * 3 * 64 + l;
                    bx0 = xf123[o]; bx1 = xf123[o + 64]; bx2 = xf123[o + 128];
                    bx4 = xf4c[((size_t)blk * TT + (m + 1)) * 16 + l15];
                }
                if (m < TT) {
                    f16x8 bh = reinterpret_cast<const f16x8*>(&H0F[cur][0][0])[l];
                    uint4 t4;
                    t4.x = (lq == 0) ? cx4.x : 0u; t4.y = (lq == 0) ? cx4.y : 0u;
                    t4.z = 0u; t4.w = 0u;
                    f32x4 accA[4], accB[4];
                    #pragma unroll
                    for (int g = 0; g < 4; ++g) {
                        accA[g] = MFMA16(h8(afu[g * 5 + 0]), bh, biasv[g]);
                        accB[g] = MFMA16(h8(afu[g * 5 + 1]), h8(cx0), ZERO4);
                        accA[g] = MFMA16(h8(afu[g * 5 + 2]), h8(cx1), accA[g]);
                        accB[g] = MFMA16(h8(afu[g * 5 + 3]), h8(cx2), accB[g]);
                        accA[g] = MFMA16(h8(afu[g * 5 + 4]), h8(t4), accA[g]);
                    }
                    float h[4];
                    #pragma unroll
                    for (int r = 0; r < 4; ++r) {
                        h[r] = lstm_cell(accA[0][r] + accB[0][r],
                                         accA[1][r] + accB[1][r],
                                         accA[2][r] + accB[2][r],
                                         accA[3][r] + accB[3][r], c[r]);
                    }
                    uint2 hp = make_uint2(pack_f16(h[0], h[1]), pack_f16(h[2], h[3]));
                    *(uint2*)FRAG_PTR(H0F[nxt], jb, l15) = hp;
                }
            } else if (w < 6) {                           // ---- L1: h1(m-1) ----
                if (m >= 1 && m <= TT) {
                    f16x8 bh0 = reinterpret_cast<const f16x8*>(&H0F[cur][0][0])[l];
                    f16x8 bh1 = reinterpret_cast<const f16x8*>(&H1F[cur][0][0])[l];
                    f16x8 bh2 = reinterpret_cast<const f16x8*>(&H1F[cur][1][0])[l];
                    f32x4 accA[4], accB[4];
                    #pragma unroll
                    for (int g = 0; g < 4; ++g) {
                        accA[g] = MFMA16(h8(afu[g * 3 + 0]), bh0, biasv[g]);
                        accB[g] = MFMA16(h8(afu[g * 3 + 1]), bh1, ZERO4);
                        accA[g] = MFMA16(h8(afu[g * 3 + 2]), bh2, accA[g]);
                    }
                    float h[4];
                    #pragma unroll
                    for (int r = 0; r < 4; ++r) {
                        h[r] = lstm_cell(accA[0][r] + accB[0][r],
                                         accA[1][r] + accB[1][r],
                                         accA[2][r] + accB[2][r],
                                         accA[3][r] + accB[3][r], c[r]);
                    }
                    uint2 hp = make_uint2(pack_f16(h[0], h[1]), pack_f16(h[2], h[3]));
                    *(uint2*)FRAG_PTR(H1F[nxt], jb, l15) = hp;
                    // NO global store here: wave 6 handles r1f next step.
                }
            } else if (w == 6) {                          // ---- store pipe ----
                if (m >= 2) {                             // store h1(t), t=m-2
                    const int t = m - 2;
                    uint4 f0 = H1F[cur][0][l];
                    uint4 f1 = H1F[cur][1][l];
                    uint4* base = r1f + ((size_t)blk * TT + t) * 128;
                    base[l]      = f0;
                    base[64 + l] = f1;
                    if ((m & 15) == 15 || m == TT + 1) {
                        asm volatile("s_waitcnt vmcnt(0)" ::: "memory");
                        if (l == 0)
                            __hip_atomic_store(&prog[blk], t, __ATOMIC_RELEASE,
                                               __HIP_MEMORY_SCOPE_AGENT);
                    }
                }
            }
            step_barrier();
        }
        // final: publish completion (wave-6 stores already drained at m=TT+1)
        if (tid == 384)
            __hip_atomic_store(&prog[blk], 4096, __ATOMIC_RELEASE,
                               __HIP_MEMORY_SCOPE_AGENT);
    } else {
        // ==================== C-role: layer 2 ====================
        const int jb = 16 * w + 4 * lq;
        uint4 af[24];
        {
            const uint4* wf4 = reinterpret_cast<const uint4*>(wfC);
            #pragma unroll
            for (int g = 0; g < 4; ++g)
                #pragma unroll
                for (int kt = 0; kt < 6; ++kt) {
                    af[g * 6 + kt] = wf4[((w * 4 + g) * 6 + kt) * 64 + l];
                    pin4(af[g * 6 + kt]);
                }
        }
        f32x4 biasv[4];
        #pragma unroll
        for (int g = 0; g < 4; ++g) {
            float sc = (g == 2) ? LOG2E2 : LOG2E;
            #pragma unroll
            for (int r = 0; r < 4; ++r)
                biasv[g][r] = b2_[g * 128 + jb + r] * sc;
        }
        if (tid < 256) H2F[0][tid >> 6][tid & 63] = (uint4){0, 0, 0, 0};

        // initial gate: first 16-step group reads r1 t <= 17
        if ((tid & 63) == 0) {
            while (__hip_atomic_load(&prog[blk], __ATOMIC_ACQUIRE,
                                     __HIP_MEMORY_SCOPE_AGENT) < 17)
                __builtin_amdgcn_s_sleep(1);
        }
        __builtin_amdgcn_s_barrier();

        // prefetch depth 2
        uint4 l00, l01, l10, l11;
        {
            size_t o = ((size_t)blk * TT) * 128 + l;
            l00 = r1f[o]; l01 = r1f[o + 64];
            l10 = r1f[o + 128]; l11 = r1f[o + 192];
        }
        step_barrier();

        float c[4] = {0.f, 0.f, 0.f, 0.f};

        #pragma unroll 2
        for (int m = 0; m < TT; ++m) {
            const int cur = m & 1, nxt = cur ^ 1;

            if ((m & 15) == 0 && m > 0) {         // gate next 16-step group
                if ((tid & 63) == 0) {            // needs t <= min(m+17, 1023)
                    const int needed = (m + 17 < TT) ? (m + 17) : (TT - 1);
                    while (__hip_atomic_load(&prog[blk], __ATOMIC_ACQUIRE,
                                             __HIP_MEMORY_SCOPE_AGENT) < needed)
                        __builtin_amdgcn_s_sleep(1);
                }
                __builtin_amdgcn_s_barrier();
            }

            uint4 cr0 = l00, cr1 = l01;
            l00 = l10; l01 = l11;
            if (m + 2 < TT) {
                size_t o = ((size_t)blk * TT + (m + 2)) * 128 + l;
                l10 = r1f[o]; l11 = r1f[o + 64];
            }

            f16x8 bh[4];
            #pragma unroll
            for (int kt = 0; kt < 4; ++kt)
                bh[kt] = reinterpret_cast<const f16x8*>(&H2F[cur][kt][0])[l];

            f32x4 accA[4], accB[4];
            #pragma unroll
            for (int g = 0; g < 4; ++g) {
                accA[g] = MFMA16(h8(af[g * 6 + 0]), h8(cr0), biasv[g]);
                accB[g] = MFMA16(h8(af[g * 6 + 1]), h8(cr1), ZERO4);
                accA[g] = MFMA16(h8(af[g * 6 + 2]), bh[0], accA[g]);
                accB[g] = MFMA16(h8(af[g * 6 + 3]), bh[1], accB[g]);
                accA[g] = MFMA16(h8(af[g * 6 + 4]), bh[2], accA[g]);
                accB[g] = MFMA16(h8(af[g * 6 + 5]), bh[3], accB[g]);
            }

            float h[4];
            #pragma unroll
            for (int r = 0; r < 4; ++r) {
                h[r] = lstm_cell(accA[0][r] + accB[0][r],
                                 accA[1][r] + accB[1][r],
                                 accA[2][r] + accB[2][r],
                                 accA[3][r] + accB[3][r], c[r]);
            }
            uint2 hp = make_uint2(pack_f16(h[0], h[1]), pack_f16(h[2], h[3]));
            *(uint2*)FRAG_PTR(H2F[nxt], jb, l15) = hp;
            f32x4 hv = (f32x4){h[0], h[1], h[2], h[3]};
            __builtin_nontemporal_store(hv, reinterpret_cast<f32x4*>(
                r2 + ((size_t)(b0b + l15) * TT + m) * 128 + jb));
            step_barrier();
        }
    }
}

// out[bt] = tanh(dot(r2[bt,:128], Wl) + bl)
__global__ __launch_bounds__(256) void final_proj(
    const float* __restrict__ r, const float* __restrict__ Wl,
    const float* __restrict__ bl, float* __restrict__ out)
{
    __shared__ float wl[128];
    const int tid = threadIdx.x;
    if (tid < 128) wl[tid] = Wl[tid];
    __syncthreads();

    const int bt = blockIdx.x * 256 + tid;
    const float4* rr = reinterpret_cast<const float4*>(r + (size_t)bt * 128);
    float a0 = 0.f, a1 = 0.f, a2 = 0.f, a3 = 0.f;
    #pragma unroll
    for (int k = 0; k < 32; ++k) {
        float4 v = rr[k];
        a0 = fmaf(v.x, wl[4 * k + 0], a0);
        a1 = fmaf(v.y, wl[4 * k + 1], a1);
        a2 = fmaf(v.z, wl[4 * k + 2], a2);
        a3 = fmaf(v.w, wl[4 * k + 3], a3);
    }
    out[bt] = tanhf(((a0 + a1) + (a2 + a3)) + bl[0]);
}

extern "C" void kernel_launch(void* const* d_in, const int* in_sizes, int n_in,
                              void* d_out, int out_size, void* d_ws, size_t ws_size,
                              hipStream_t stream) {
    const float* input = (const float*)d_in[0];
    const float* h_0   = (const float*)d_in[1];
    const float* c_0   = (const float*)d_in[2];
    const float* Wih0  = (const float*)d_in[3];
    const float* Whh0  = (const float*)d_in[4];
    const float* b0    = (const float*)d_in[5];
    const float* Wih1  = (const float*)d_in[6];
    const float* Whh1  = (const float*)d_in[7];
    const float* b1    = (const float*)d_in[8];
    const float* Wih2  = (const float*)d_in[9];
    const float* Whh2  = (const float*)d_in[10];
    const float* b2    = (const float*)d_in[11];
    const float* Wl    = (const float*)d_in[12];
    const float* bl    = (const float*)d_in[13];

    float* out = (float*)d_out;                 // [B*T] head output
    float* r2  = out + (size_t)BB * TT;         // [B,T,128] second output

    char* ws = (char*)d_ws;
    uint4*    xf123 = (uint4*)ws;                          // 50,331,648 B
    uint2*    xf4c  = (uint2*)(ws + 50331648);             //  2,097,152 B
    uint4*    r1f   = (uint4*)(ws + 52428800);             // 33,554,432 B
    _Float16* wfA0  = (_Float16*)(ws + 85983232);          //     40,960 B
    _Float16* wfA1  = (_Float16*)(ws + 86024192);          //     49,152 B
    _Float16* wfC   = (_Float16*)(ws + 86073344);          //    196,608 B
    int*      prog  = (int*)(ws + 86269952);               //         64 B

    hipLaunchKernelGGL(prep, dim3(561 + 13312), dim3(256), 0, stream,
                       Wih0, Whh0, Wih1, Whh1, Wih2, Whh2, input,
                       wfA0, wfA1, wfC, prog, xf123, xf4c);
    hipLaunchKernelGGL(lstm_mega, dim3(2 * NBLK), dim3(512), 0, stream,
                       xf123, xf4c, wfA0, wfA1, wfC, b0, b1, b2, h_0, c_0,
                       r1f, r2, prog);
    hipLaunchKernelGGL(final_proj, dim3(BB * TT / 256), dim3(256), 0, stream,
                       r2, Wl, bl, out);
}

// Round 17
// 1281.570 us; speedup vs baseline: 1.1266x; 1.1266x over previous
//
#include <hip/hip_runtime.h>
#include <cmath>

#define TT 1024
#define BB 256
#define GG 16            // batch elements per block (MFMA N)
#define NBLK (BB / GG)   // 16 producer blocks + 16 consumer blocks

#define LOG2E  1.4426950408889634f
#define LOG2E2 2.8853900817779268f   // 2*log2(e)

typedef _Float16 f16x8 __attribute__((ext_vector_type(8)));
typedef float    f32x4 __attribute__((ext_vector_type(4)));
typedef _Float16 half2v __attribute__((ext_vector_type(2)));

__device__ __forceinline__ float fast_rcp(float x) { return __builtin_amdgcn_rcpf(x); }
// inputs PRE-SCALED by log2e (sig) / 2log2e (tanh) via weights+biases
__device__ __forceinline__ float sig2(float g) { return fast_rcp(1.0f + __builtin_exp2f(-g)); }
__device__ __forceinline__ float th2(float g)  { return 1.0f - 2.0f * fast_rcp(1.0f + __builtin_exp2f(g)); }
__device__ __forceinline__ unsigned pack_f16(float a, float b) {
    half2v h; h.x = (_Float16)a; h.y = (_Float16)b;
    return __builtin_bit_cast(unsigned, h);
}
__device__ __forceinline__ void pin4(uint4& u) {
    asm volatile("" : "+v"(u.x), "+v"(u.y), "+v"(u.z), "+v"(u.w));
}
__device__ __forceinline__ f16x8 h8(uint4 u) { return __builtin_bit_cast(f16x8, u); }
// LDS-ordered barrier that does NOT drain vmcnt (global stores stay in flight).
__device__ __forceinline__ void step_barrier() {
    asm volatile("s_waitcnt lgkmcnt(0)" ::: "memory");
    __builtin_amdgcn_s_barrier();
}

#define MFMA16(a, b, c) __builtin_amdgcn_mfma_f32_16x16x32_f16((a), (b), (c), 0, 0, 0)
#define ZERO4 ((f32x4){0.f, 0.f, 0.f, 0.f})

// Fragment addressing: element (k, col) of a B-frag tile set lives at
// buf[k>>5][((k&31)>>3)*16 + col] byte (k&7)*2.
#define FRAG_PTR(buf, k, col) ((char*)&(buf)[(k) >> 5][(((k) & 31) >> 3) * 16 + (col)] + ((k) & 7) * 2)

// ============================================================================
// prep = weight reorder (fp16 A-frags, pre-scaled) + x pre-pack + prog zero.
// Blocks [0,561) = reorder+flags; [561, 561+13312) = x pre-pack.
// ============================================================================
__global__ __launch_bounds__(256) void prep(
    const float* __restrict__ Wih0, const float* __restrict__ Whh0,
    const float* __restrict__ Wih1, const float* __restrict__ Whh1,
    const float* __restrict__ Wih2, const float* __restrict__ Whh2,
    const float* __restrict__ x,
    _Float16* __restrict__ wfA0, _Float16* __restrict__ wfA1,
    _Float16* __restrict__ wfC, int* __restrict__ prog,
    uint4* __restrict__ xf123, uint2* __restrict__ xf4c)
{
    if (blockIdx.x < 561) {
        int idx = blockIdx.x * 256 + threadIdx.x;
        if (idx < 98304) {                       // C section
            int j = idx & 7, l = (idx >> 3) & 63, t = idx >> 9;
            int kt = t % 6, g = (t / 6) & 3, w = t / 24;
            int row = g * 128 + 16 * w + (l & 15);
            int k = kt * 32 + ((l >> 4) << 3) + j;
            float sc = (g == 2) ? LOG2E2 : LOG2E;
            float v = (k < 64) ? Wih2[row * 64 + k] : Whh2[row * 128 + (k - 64)];
            wfC[idx] = (_Float16)(v * sc);
        } else if (idx < 118784) {               // A0 section: K-order [h0|x|pad]
            int f = idx - 98304;
            int j = f & 7, l = (f >> 3) & 63, t = f >> 9;
            int kt = t % 5, g = (t / 5) & 3, w = t / 20;
            int row = g * 32 + 16 * w + (l & 15);
            int k = kt * 32 + ((l >> 4) << 3) + j;
            float sc = (g == 2) ? LOG2E2 : LOG2E;
            float v = (k < 32)  ? Whh0[row * 32 + k]
                    : (k < 132) ? Wih0[row * 100 + (k - 32)] : 0.0f;
            wfA0[f] = (_Float16)(v * sc);
        } else if (idx < 143360) {               // A1 section
            int f = idx - 118784;
            int j = f & 7, l = (f >> 3) & 63, t = f >> 9;
            int kt = t % 3, g = (t / 3) & 3, w = t / 12;
            int row = g * 64 + 16 * w + (l & 15);
            int k = kt * 32 + ((l >> 4) << 3) + j;
            float sc = (g == 2) ? LOG2E2 : LOG2E;
            float v = (k < 32) ? Wih1[row * 32 + k] : Whh1[row * 64 + (k - 32)];
            wfA1[f] = (_Float16)(v * sc);
        } else if (idx < 143376) {               // progress flags
            prog[idx - 143360] = 0;
        }
    } else {
        int idx = (blockIdx.x - 561) * 256 + threadIdx.x;
        if (idx < 16 * 1024 * 3 * 64) {
            int l   = idx & 63;
            int kt  = (idx >> 6) % 3;
            int t   = ((idx >> 6) / 3) & 1023;
            int blk = (idx >> 6) / 3 / 1024;
            int col = l & 15, lq = l >> 4;
            int xidx = kt * 32 + lq * 8;
            const float* xr = x + ((size_t)(blk * GG + col) * TT + t) * 100 + xidx;
            float4 a = *reinterpret_cast<const float4*>(xr);
            float4 b = *reinterpret_cast<const float4*>(xr + 4);
            uint4 u;
            u.x = pack_f16(a.x, a.y); u.y = pack_f16(a.z, a.w);
            u.z = pack_f16(b.x, b.y); u.w = pack_f16(b.z, b.w);
            xf123[idx] = u;
        } else {
            int f = idx - 16 * 1024 * 3 * 64;     // exactly 16*1024*16 threads
            int col = f & 15;
            int t   = (f >> 4) & 1023;
            int blk = f >> 14;
            const float* xr = x + ((size_t)(blk * GG + col) * TT + t) * 100 + 96;
            float4 a = *reinterpret_cast<const float4*>(xr);
            uint2 u; u.x = pack_f16(a.x, a.y); u.y = pack_f16(a.z, a.w);
            xf4c[f] = u;
        }
    }
}

// ============================================================================
// Mega kernel: 32 blocks x 512 threads. R15 structure + pointer-bump
// addressing (constant-stride pointer increments instead of per-step 64-bit
// index arithmetic) on all per-step global accesses.
//   blocks 0..15  = A-role: L0 (waves 0-1) + L1 (waves 2-5, lagged 1 step);
//                   wave 6 = store pipeline (r1f stores + drains + publish
//                   every 16 steps).
//   blocks 16..31 = C-role: L2, gated every 16 steps, prefetch depth 2,
//                   nontemporal r2 stores.
// ============================================================================
__global__ __attribute__((amdgpu_flat_work_group_size(512, 512),
                          amdgpu_waves_per_eu(1, 2)))
void lstm_mega(const uint4* __restrict__ xf123,
               const uint2* __restrict__ xf4c,
               const _Float16* __restrict__ wfA0,
               const _Float16* __restrict__ wfA1,
               const _Float16* __restrict__ wfC,
               const float* __restrict__ b0_,     // [128]
               const float* __restrict__ b1_,     // [256]
               const float* __restrict__ b2_,     // [512]
               const float* __restrict__ h_0,     // [1, B, 32]
               const float* __restrict__ c_0,     // [1, B, 32]
               uint4* __restrict__ r1f,           // [16][1024][2][64]
               float* __restrict__ r2,            // [B, T, 128]
               int* __restrict__ prog)            // [16]
{
    const int tid = threadIdx.x;
    const int w = tid >> 6, l = tid & 63;
    const int l15 = l & 15, lq = l >> 4;
    const bool isA = (blockIdx.x < NBLK);
    const int blk = isA ? blockIdx.x : blockIdx.x - NBLK;
    const int b0b = blk * GG;

    __shared__ alignas(16) uint4 H0F[2][1][64];   // A: h0 frag
    __shared__ alignas(16) uint4 H1F[2][2][64];   // A: h1 frags
    __shared__ alignas(16) uint4 H2F[2][4][64];   // C: h2 frags

    if (isA) {
        // ==================== A-role: layers 0+1 ====================
        uint4 afu[20];
        f32x4 biasv[4];
        float c[4] = {0.f, 0.f, 0.f, 0.f};
        int jb = 0;
        if (w < 2) {                               // L0
            jb = 16 * w + 4 * lq;
            const uint4* wf4 = reinterpret_cast<const uint4*>(wfA0);
            #pragma unroll
            for (int g = 0; g < 4; ++g)
                #pragma unroll
                for (int kt = 0; kt < 5; ++kt) {
                    afu[g * 5 + kt] = wf4[((w * 4 + g) * 5 + kt) * 64 + l];
                    pin4(afu[g * 5 + kt]);
                }
            #pragma unroll
            for (int g = 0; g < 4; ++g) {
                float sc = (g == 2) ? LOG2E2 : LOG2E;
                #pragma unroll
                for (int r = 0; r < 4; ++r)
                    biasv[g][r] = b0_[g * 32 + jb + r] * sc;
            }
            #pragma unroll
            for (int r = 0; r < 4; ++r) c[r] = c_0[(b0b + l15) * 32 + jb + r];
        } else if (w < 6) {                        // L1
            const int w1 = w - 2;
            jb = 16 * w1 + 4 * lq;
            const uint4* wf4 = reinterpret_cast<const uint4*>(wfA1);
            #pragma unroll
            for (int g = 0; g < 4; ++g)
                #pragma unroll
                for (int kt = 0; kt < 3; ++kt) {
                    afu[g * 3 + kt] = wf4[((w1 * 4 + g) * 3 + kt) * 64 + l];
                    pin4(afu[g * 3 + kt]);
                }
            #pragma unroll
            for (int g = 0; g < 4; ++g) {
                float sc = (g == 2) ? LOG2E2 : LOG2E;
                #pragma unroll
                for (int r = 0; r < 4; ++r)
                    biasv[g][r] = b1_[g * 64 + jb + r] * sc;
            }
        }

        {   // init LDS: H0F[0] = h_0; H1F[1] = 0
            int col = tid >> 5, u = tid & 31;
            *(_Float16*)FRAG_PTR(H0F[0], u, col) =
                (_Float16)h_0[(b0b + col) * 32 + u];
            if (tid < 128) H1F[1][tid >> 6][tid & 63] = (uint4){0, 0, 0, 0};
        }

        // L0 x prefetch (t=0) + bump pointers for t>=1
        uint4 bx0 = {0,0,0,0}, bx1 = {0,0,0,0}, bx2 = {0,0,0,0};
        uint2 bx4 = {0, 0};
        const uint4* xp  = xf123 + (size_t)blk * TT * 192 + l;
        const uint2* x4p = xf4c  + (size_t)blk * TT * 16  + l15;
        if (w < 2) {
            bx0 = xp[0]; bx1 = xp[64]; bx2 = xp[128];
            bx4 = *x4p;
        }
        xp += 192; x4p += 16;                      // -> t=1
        // wave-6 store pointer (starts at t=0)
        uint4* r1p = r1f + (size_t)blk * TT * 128 + l;
        step_barrier();

        #pragma unroll 2
        for (int m = 0; m <= TT + 1; ++m) {           // 1026 iters (even)
            const int cur = m & 1, nxt = cur ^ 1;

            if (w < 2) {                                  // ---- L0: h0(m) ----
                uint4 cx0 = bx0, cx1 = bx1, cx2 = bx2;
                uint2 cx4 = bx4;
                if (m + 1 < TT) {
                    bx0 = xp[0]; bx1 = xp[64]; bx2 = xp[128];
                    bx4 = *x4p;
                    xp += 192; x4p += 16;
                }
                if (m < TT) {
                    f16x8 bh = reinterpret_cast<const f16x8*>(&H0F[cur][0][0])[l];
                    uint4 t4;
                    t4.x = (lq == 0) ? cx4.x : 0u; t4.y = (lq == 0) ? cx4.y : 0u;
                    t4.z = 0u; t4.w = 0u;
                    f32x4 accA[4], accB[4];
                    #pragma unroll
                    for (int g = 0; g < 4; ++g) {
                        accA[g] = MFMA16(h8(afu[g * 5 + 0]), bh, biasv[g]);
                        accB[g] = MFMA16(h8(afu[g * 5 + 1]), h8(cx0), ZERO4);
                        accA[g] = MFMA16(h8(afu[g * 5 + 2]), h8(cx1), accA[g]);
                        accB[g] = MFMA16(h8(afu[g * 5 + 3]), h8(cx2), accB[g]);
                        accA[g] = MFMA16(h8(afu[g * 5 + 4]), h8(t4), accA[g]);
                    }
                    float h[4];
                    #pragma unroll
                    for (int r = 0; r < 4; ++r) {
                        float ai  = sig2(accA[0][r] + accB[0][r]);
                        float afg = sig2(accA[1][r] + accB[1][r]);
                        float ag  = th2(accA[2][r] + accB[2][r]);
                        float ao  = sig2(accA[3][r] + accB[3][r]);
                        c[r] = fmaf(afg, c[r], ai * ag);
                        h[r] = ao * th2(c[r] * LOG2E2);
                    }
                    uint2 hp = make_uint2(pack_f16(h[0], h[1]), pack_f16(h[2], h[3]));
                    *(uint2*)FRAG_PTR(H0F[nxt], jb, l15) = hp;
                }
            } else if (w < 6) {                           // ---- L1: h1(m-1) ----
                if (m >= 1 && m <= TT) {
                    f16x8 bh0 = reinterpret_cast<const f16x8*>(&H0F[cur][0][0])[l];
                    f16x8 bh1 = reinterpret_cast<const f16x8*>(&H1F[cur][0][0])[l];
                    f16x8 bh2 = reinterpret_cast<const f16x8*>(&H1F[cur][1][0])[l];
                    f32x4 accA[4], accB[4];
                    #pragma unroll
                    for (int g = 0; g < 4; ++g) {
                        accA[g] = MFMA16(h8(afu[g * 3 + 0]), bh0, biasv[g]);
                        accB[g] = MFMA16(h8(afu[g * 3 + 1]), bh1, ZERO4);
                        accA[g] = MFMA16(h8(afu[g * 3 + 2]), bh2, accA[g]);
                    }
                    float h[4];
                    #pragma unroll
                    for (int r = 0; r < 4; ++r) {
                        float ai  = sig2(accA[0][r] + accB[0][r]);
                        float afg = sig2(accA[1][r] + accB[1][r]);
                        float ag  = th2(accA[2][r] + accB[2][r]);
                        float ao  = sig2(accA[3][r] + accB[3][r]);
                        c[r] = fmaf(afg, c[r], ai * ag);
                        h[r] = ao * th2(c[r] * LOG2E2);
                    }
                    uint2 hp = make_uint2(pack_f16(h[0], h[1]), pack_f16(h[2], h[3]));
                    *(uint2*)FRAG_PTR(H1F[nxt], jb, l15) = hp;
                    // NO global store here: wave 6 handles r1f next step.
                }
            } else if (w == 6) {                          // ---- store pipe ----
                if (m >= 2) {                             // store h1(t), t=m-2
                    const int t = m - 2;
                    uint4 f0 = H1F[cur][0][l];
                    uint4 f1 = H1F[cur][1][l];
                    r1p[0]  = f0;
                    r1p[64] = f1;
                    r1p += 128;
                    if ((m & 15) == 15 || m == TT + 1) {
                        asm volatile("s_waitcnt vmcnt(0)" ::: "memory");
                        if (l == 0)
                            __hip_atomic_store(&prog[blk], t, __ATOMIC_RELEASE,
                                               __HIP_MEMORY_SCOPE_AGENT);
                    }
                }
            }
            step_barrier();
        }
        // final: publish completion (wave-6 stores already drained at m=TT+1)
        if (tid == 384)
            __hip_atomic_store(&prog[blk], 4096, __ATOMIC_RELEASE,
                               __HIP_MEMORY_SCOPE_AGENT);
    } else {
        // ==================== C-role: layer 2 ====================
        const int jb = 16 * w + 4 * lq;
        uint4 af[24];
        {
            const uint4* wf4 = reinterpret_cast<const uint4*>(wfC);
            #pragma unroll
            for (int g = 0; g < 4; ++g)
                #pragma unroll
                for (int kt = 0; kt < 6; ++kt) {
                    af[g * 6 + kt] = wf4[((w * 4 + g) * 6 + kt) * 64 + l];
                    pin4(af[g * 6 + kt]);
                }
        }
        f32x4 biasv[4];
        #pragma unroll
        for (int g = 0; g < 4; ++g) {
            float sc = (g == 2) ? LOG2E2 : LOG2E;
            #pragma unroll
            for (int r = 0; r < 4; ++r)
                biasv[g][r] = b2_[g * 128 + jb + r] * sc;
        }
        if (tid < 256) H2F[0][tid >> 6][tid & 63] = (uint4){0, 0, 0, 0};

        // initial gate: first 16-step group reads r1 t <= 17
        if ((tid & 63) == 0) {
            while (__hip_atomic_load(&prog[blk], __ATOMIC_ACQUIRE,
                                     __HIP_MEMORY_SCOPE_AGENT) < 17)
                __builtin_amdgcn_s_sleep(1);
        }
        __builtin_amdgcn_s_barrier();

        // prefetch depth 2 (t=0,1); rp then points at t=2
        uint4 l00, l01, l10, l11;
        const uint4* rp = r1f + (size_t)blk * TT * 128 + l;
        {
            l00 = rp[0];   l01 = rp[64];
            l10 = rp[128]; l11 = rp[192];
            rp += 256;
        }
        float* r2p = r2 + (size_t)(b0b + l15) * TT * 128 + jb;
        step_barrier();

        float c[4] = {0.f, 0.f, 0.f, 0.f};

        #pragma unroll 2
        for (int m = 0; m < TT; ++m) {
            const int cur = m & 1, nxt = cur ^ 1;

            if ((m & 15) == 0 && m > 0) {         // gate next 16-step group
                if ((tid & 63) == 0) {            // needs t <= min(m+17, 1023)
                    const int needed = (m + 17 < TT) ? (m + 17) : (TT - 1);
                    while (__hip_atomic_load(&prog[blk], __ATOMIC_ACQUIRE,
                                             __HIP_MEMORY_SCOPE_AGENT) < needed)
                        __builtin_amdgcn_s_sleep(1);
                }
                __builtin_amdgcn_s_barrier();
            }

            uint4 cr0 = l00, cr1 = l01;
            l00 = l10; l01 = l11;
            if (m + 2 < TT) {
                l10 = rp[0]; l11 = rp[64];
                rp += 128;
            }

            f16x8 bh[4];
            #pragma unroll
            for (int kt = 0; kt < 4; ++kt)
                bh[kt] = reinterpret_cast<const f16x8*>(&H2F[cur][kt][0])[l];

            f32x4 accA[4], accB[4];
            #pragma unroll
            for (int g = 0; g < 4; ++g) {
                accA[g] = MFMA16(h8(af[g * 6 + 0]), h8(cr0), biasv[g]);
                accB[g] = MFMA16(h8(af[g * 6 + 1]), h8(cr1), ZERO4);
                accA[g] = MFMA16(h8(af[g * 6 + 2]), bh[0], accA[g]);
                accB[g] = MFMA16(h8(af[g * 6 + 3]), bh[1], accB[g]);
                accA[g] = MFMA16(h8(af[g * 6 + 4]), bh[2], accA[g]);
                accB[g] = MFMA16(h8(af[g * 6 + 5]), bh[3], accB[g]);
            }

            float h[4];
            #pragma unroll
            for (int r = 0; r < 4; ++r) {
                float ai  = sig2(accA[0][r] + accB[0][r]);
                float afg = sig2(accA[1][r] + accB[1][r]);
                float ag  = th2(accA[2][r] + accB[2][r]);
                float ao  = sig2(accA[3][r] + accB[3][r]);
                c[r] = fmaf(afg, c[r], ai * ag);
                h[r] = ao * th2(c[r] * LOG2E2);
            }
            uint2 hp = make_uint2(pack_f16(h[0], h[1]), pack_f16(h[2], h[3]));
            *(uint2*)FRAG_PTR(H2F[nxt], jb, l15) = hp;
            f32x4 hv = (f32x4){h[0], h[1], h[2], h[3]};
            __builtin_nontemporal_store(hv, reinterpret_cast<f32x4*>(r2p));
            r2p += 128;
            step_barrier();
        }
    }
}

// out[bt] = tanh(dot(r2[bt,:128], Wl) + bl)
__global__ __launch_bounds__(256) void final_proj(
    const float* __restrict__ r, const float* __restrict__ Wl,
    const float* __restrict__ bl, float* __restrict__ out)
{
    __shared__ float wl[128];
    const int tid = threadIdx.x;
    if (tid < 128) wl[tid] = Wl[tid];
    __syncthreads();

    const int bt = blockIdx.x * 256 + tid;
    const float4* rr = reinterpret_cast<const float4*>(r + (size_t)bt * 128);
    float a0 = 0.f, a1 = 0.f, a2 = 0.f, a3 = 0.f;
    #pragma unroll
    for (int k = 0; k < 32; ++k) {
        float4 v = rr[k];
        a0 = fmaf(v.x, wl[4 * k + 0], a0);
        a1 = fmaf(v.y, wl[4 * k + 1], a1);
        a2 = fmaf(v.z, wl[4 * k + 2], a2);
        a3 = fmaf(v.w, wl[4 * k + 3], a3);
    }
    out[bt] = tanhf(((a0 + a1) + (a2 + a3)) + bl[0]);
}

extern "C" void kernel_launch(void* const* d_in, const int* in_sizes, int n_in,
                              void* d_out, int out_size, void* d_ws, size_t ws_size,
                              hipStream_t stream) {
    const float* input = (const float*)d_in[0];
    const float* h_0   = (const float*)d_in[1];
    const float* c_0   = (const float*)d_in[2];
    const float* Wih0  = (const float*)d_in[3];
    const float* Whh0  = (const float*)d_in[4];
    const float* b0    = (const float*)d_in[5];
    const float* Wih1  = (const float*)d_in[6];
    const float* Whh1  = (const float*)d_in[7];
    const float* b1    = (const float*)d_in[8];
    const float* Wih2  = (const float*)d_in[9];
    const float* Whh2  = (const float*)d_in[10];
    const float* b2    = (const float*)d_in[11];
    const float* Wl    = (const float*)d_in[12];
    const float* bl    = (const float*)d_in[13];

    float* out = (float*)d_out;                 // [B*T] head output
    float* r2  = out + (size_t)BB * TT;         // [B,T,128] second output

    char* ws = (char*)d_ws;
    uint4*    xf123 = (uint4*)ws;                          // 50,331,648 B
    uint2*    xf4c  = (uint2*)(ws + 50331648);             //  2,097,152 B
    uint4*    r1f   = (uint4*)(ws + 52428800);             // 33,554,432 B
    _Float16* wfA0  = (_Float16*)(ws + 85983232);          //     40,960 B
    _Float16* wfA1  = (_Float16*)(ws + 86024192);          //     49,152 B
    _Float16* wfC   = (_Float16*)(ws + 86073344);          //    196,608 B
    int*      prog  = (int*)(ws + 86269952);               //         64 B

    hipLaunchKernelGGL(prep, dim3(561 + 13312), dim3(256), 0, stream,
                       Wih0, Whh0, Wih1, Whh1, Wih2, Whh2, input,
                       wfA0, wfA1, wfC, prog, xf123, xf4c);
    hipLaunchKernelGGL(lstm_mega, dim3(2 * NBLK), dim3(512), 0, stream,
                       xf123, xf4c, wfA0, wfA1, wfC, b0, b1, b2, h_0, c_0,
                       r1f, r2, prog);
    hipLaunchKernelGGL(final_proj, dim3(BB * TT / 256), dim3(256), 0, stream,
                       r2, Wl, bl, out);
}